// Round 1
// baseline (203.112 us; speedup 1.0000x reference)
//
#include <hip/hip_runtime.h>
#include <hip/hip_bf16.h>

#define B_DIM 64
#define T_DIM 512
#define H_DIM 1024

typedef __attribute__((ext_vector_type(8))) __bf16 bf16x8;
typedef __attribute__((ext_vector_type(4))) float f32x4;

// ws layout (bytes)
#define PREVBF_OFF 0UL            // 64*512*1024*2 = 67108864
#define WBF_OFF    67108864UL     // 1024*1024*2   =  2097152
#define DEC_OFF    69206016UL     // 64*1024*4     =   262144
#define PART_OFF   69468160UL     // 32768*8*4     =  1048576
#define AT_OFF     70516736UL     // 32768*4       =   131072
// total 70647808 bytes

__device__ __forceinline__ unsigned short f2bf(float x) {
  unsigned u = __float_as_uint(x);
  unsigned r = (u + 0x7FFFu + ((u >> 16) & 1u)) >> 16;  // RNE
  return (unsigned short)r;
}
__device__ __forceinline__ float bf2f(unsigned short u) {
  return __uint_as_float(((unsigned)u) << 16);
}

__device__ __forceinline__ void gload_lds16(const void* g, void* l) {
  __builtin_amdgcn_global_load_lds(
      (const __attribute__((address_space(1))) void*)g,
      (__attribute__((address_space(3))) void*)l, 16, 0, 0);
}

// K1: copy prev_s -> out (concat region), convert prev_s -> bf16 ws,
//     copy s_t -> out tail row, convert W_prev -> bf16 ws.
__global__ void prep_kernel(const float* __restrict__ prev,
                            const float* __restrict__ st,
                            const float* __restrict__ Wp,
                            float* __restrict__ out,
                            unsigned short* __restrict__ prevbf,
                            unsigned short* __restrict__ wbf) {
  const long P4 = (long)B_DIM * T_DIM * H_DIM / 4;  // 8388608
  const long S4 = (long)B_DIM * H_DIM / 4;          // 16384
  const long W4 = (long)H_DIM * H_DIM / 4;          // 262144
  const long total = P4 + S4 + W4;
  long stride = (long)gridDim.x * blockDim.x;
  for (long i = (long)blockIdx.x * blockDim.x + threadIdx.x; i < total; i += stride) {
    if (i < P4) {
      float4 f = ((const float4*)prev)[i];
      long elem = i * 4;
      int b = (int)(elem >> 19);               // /(T*H)
      long rem = elem & ((1L << 19) - 1);
      ((float4*)out)[16384 + (long)b * 131328 + (rem >> 2)] = f;
      ushort4 u;
      u.x = f2bf(f.x); u.y = f2bf(f.y); u.z = f2bf(f.z); u.w = f2bf(f.w);
      ((ushort4*)prevbf)[i] = u;
    } else if (i < P4 + S4) {
      long j = i - P4;
      float4 f = ((const float4*)st)[j];
      long elem = j * 4;
      int b = (int)(elem >> 10);
      int h = (int)(elem & 1023);
      ((float4*)out)[16384 + (long)b * 131328 + 131072 + (h >> 2)] = f;
    } else {
      long j = i - P4 - S4;
      float4 f = ((const float4*)Wp)[j];
      ushort4 u;
      u.x = f2bf(f.x); u.y = f2bf(f.y); u.z = f2bf(f.z); u.w = f2bf(f.w);
      ((ushort4*)wbf)[j] = u;
    }
  }
}

// K2: dec_fea[b][o] = sum_h s_t[b][h]*W_s[o][h] + b_s[o]
// one wave per o; W row held in registers; loop over b (s_t served by L2).
__global__ void dec_kernel(const float* __restrict__ st,
                           const float* __restrict__ Ws,
                           const float* __restrict__ bs,
                           float* __restrict__ dec) {
  int tid = threadIdx.x;
  int lane = tid & 63, w = tid >> 6;
  int o = blockIdx.x * 4 + w;
  const float4* wrow = (const float4*)(Ws + (size_t)o * H_DIM);
  float4 w0 = wrow[lane], w1 = wrow[64 + lane], w2 = wrow[128 + lane], w3 = wrow[192 + lane];
  const float4* st4 = (const float4*)st;
  float bias = bs[o];
  #pragma unroll 8
  for (int b = 0; b < B_DIM; b++) {
    const float4* s = st4 + (size_t)b * 256;
    float4 s0 = s[lane], s1 = s[64 + lane], s2 = s[128 + lane], s3 = s[192 + lane];
    float p = w0.x * s0.x + w0.y * s0.y + w0.z * s0.z + w0.w * s0.w
            + w1.x * s1.x + w1.y * s1.y + w1.z * s1.z + w1.w * s1.w
            + w2.x * s2.x + w2.y * s2.y + w2.z * s2.z + w2.w * s2.w
            + w3.x * s3.x + w3.y * s3.y + w3.z * s3.z + w3.w * s3.w;
    p += __shfl_xor(p, 1);  p += __shfl_xor(p, 2);
    p += __shfl_xor(p, 4);  p += __shfl_xor(p, 8);
    p += __shfl_xor(p, 16); p += __shfl_xor(p, 32);
    if (lane == 0) dec[(size_t)b * H_DIM + o] = p + bias;
  }
}

// K3: scores partials. et = A(bf16 prev_s)[M,K] x W(bf16)[N,K]^T, fused
// epilogue: part[m][ntile] = sum_{o in tile} tanh(et+dec)*v[o].
__global__ __launch_bounds__(256, 2) void score_gemm(
    const unsigned short* __restrict__ A,   // [32768][1024] bf16
    const unsigned short* __restrict__ Bw,  // [1024][1024] bf16
    const float* __restrict__ dec,          // [64][1024]
    const float* __restrict__ v,            // [1024]
    float* __restrict__ part)               // [32768][8]
{
  __shared__ __align__(16) unsigned short ldsA[128 * 64];
  __shared__ __align__(16) unsigned short ldsB[128 * 64];

  int orig = blockIdx.x;                       // 2048 blocks
  int swz = (orig & 7) * 256 + (orig >> 3);    // bijective XCD swizzle
  int bm = swz >> 3, bn = swz & 7;

  int tid = threadIdx.x;
  int lane = tid & 63, w = tid >> 6;
  size_t m0 = (size_t)bm * 128;
  int n0 = bn * 128;

  f32x4 acc[2][8];
  #pragma unroll
  for (int i = 0; i < 2; i++)
    #pragma unroll
    for (int j = 0; j < 8; j++) {
      f32x4 z; z.x = 0.f; z.y = 0.f; z.z = 0.f; z.w = 0.f;
      acc[i][j] = z;
    }

  int lr = lane >> 4, lc = lane & 15;

  for (int k0 = 0; k0 < 1024; k0 += 64) {
    __syncthreads();  // LDS free from previous iteration's reads
    #pragma unroll
    for (int i = 0; i < 4; i++) {
      int idx = i * 256 + tid;
      int row = idx >> 3, sub = idx & 7;
      gload_lds16(A + (m0 + row) * 1024 + k0 + sub * 8, &ldsA[idx * 8]);
    }
    #pragma unroll
    for (int i = 0; i < 4; i++) {
      int idx = i * 256 + tid;
      int row = idx >> 3, sub = idx & 7;
      gload_lds16(Bw + (size_t)(n0 + row) * 1024 + k0 + sub * 8, &ldsB[idx * 8]);
    }
    asm volatile("s_waitcnt vmcnt(0)" ::: "memory");
    __syncthreads();

    #pragma unroll
    for (int kk = 0; kk < 2; kk++) {
      bf16x8 a0 = *(const bf16x8*)&ldsA[(w * 32 + 0  + lc) * 64 + kk * 32 + lr * 8];
      bf16x8 a1 = *(const bf16x8*)&ldsA[(w * 32 + 16 + lc) * 64 + kk * 32 + lr * 8];
      bf16x8 bfr[8];
      #pragma unroll
      for (int fn = 0; fn < 8; fn++)
        bfr[fn] = *(const bf16x8*)&ldsB[(fn * 16 + lc) * 64 + kk * 32 + lr * 8];
      #pragma unroll
      for (int fn = 0; fn < 8; fn++) {
        acc[0][fn] = __builtin_amdgcn_mfma_f32_16x16x32_bf16(a0, bfr[fn], acc[0][fn], 0, 0, 0);
        acc[1][fn] = __builtin_amdgcn_mfma_f32_16x16x32_bf16(a1, bfr[fn], acc[1][fn], 0, 0, 0);
      }
    }
  }

  // epilogue: tanh + dot v, reduce over the 128 cols of this n-tile
  int b = (int)(m0 >> 9);  // /T_DIM
  float dv[8], vv[8];
  #pragma unroll
  for (int fn = 0; fn < 8; fn++) {
    int col = n0 + fn * 16 + lc;
    dv[fn] = dec[(size_t)b * H_DIM + col];
    vv[fn] = v[col];
  }
  #pragma unroll
  for (int fm = 0; fm < 2; fm++) {
    #pragma unroll
    for (int r = 0; r < 4; r++) {
      float s = 0.f;
      #pragma unroll
      for (int fn = 0; fn < 8; fn++) {
        float x = acc[fm][fn][r] + dv[fn];
        x = fminf(fmaxf(x, -15.f), 15.f);
        float e = __expf(2.f * x);
        s += vv[fn] * (e - 1.f) * __builtin_amdgcn_rcpf(e + 1.f);
      }
      s += __shfl_xor(s, 1); s += __shfl_xor(s, 2);
      s += __shfl_xor(s, 4); s += __shfl_xor(s, 8);
      if (lc == 0) {
        size_t m = m0 + (size_t)w * 32 + fm * 16 + lr * 4 + r;
        part[m * 8 + bn] = s;
      }
    }
  }
}

// K4: softmax over T per batch row
__global__ void softmax_kernel(const float* __restrict__ part, float* __restrict__ at) {
  int b = blockIdx.x, tid = threadIdx.x;
  __shared__ float sc[512];
  __shared__ float red[8];
  #pragma unroll
  for (int rep = 0; rep < 2; rep++) {
    int t = rep * 256 + tid;
    const float* p = part + ((size_t)b * 512 + t) * 8;
    sc[t] = p[0] + p[1] + p[2] + p[3] + p[4] + p[5] + p[6] + p[7];
  }
  __syncthreads();
  float m = fmaxf(sc[tid], sc[tid + 256]);
  for (int d = 1; d < 64; d <<= 1) m = fmaxf(m, __shfl_xor(m, d));
  if ((tid & 63) == 0) red[tid >> 6] = m;
  __syncthreads();
  m = fmaxf(fmaxf(red[0], red[1]), fmaxf(red[2], red[3]));
  float e0 = __expf(sc[tid] - m), e1 = __expf(sc[tid + 256] - m);
  float s = e0 + e1;
  for (int d = 1; d < 64; d <<= 1) s += __shfl_xor(s, d);
  if ((tid & 63) == 0) red[4 + (tid >> 6)] = s;
  __syncthreads();
  s = red[4] + red[5] + red[6] + red[7];
  float inv = 1.f / s;
  at[(size_t)b * 512 + tid] = e0 * inv;
  at[(size_t)b * 512 + tid + 256] = e1 * inv;
}

// K5: ct_d[b][h] = sum_t at[b][t]*prev_s[b][t][h]  (bf16 prev, fp32 acc)
__global__ void ctd_kernel(const unsigned short* __restrict__ pbf,
                           const float* __restrict__ at, float* __restrict__ out) {
  int blk = blockIdx.x;                 // 512 = 64 b * 8 tchunks
  int b = blk >> 3, tc = blk & 7;
  int tid = threadIdx.x;
  int h = tid * 4;
  float a0 = 0.f, a1 = 0.f, a2 = 0.f, a3 = 0.f;
  const unsigned short* base = pbf + ((size_t)b * T_DIM + (size_t)tc * 64) * H_DIM + h;
  const float* atb = at + (size_t)b * T_DIM + tc * 64;
  #pragma unroll 4
  for (int i = 0; i < 64; i++) {
    float a = atb[i];
    ushort4 u = *(const ushort4*)(base + (size_t)i * H_DIM);
    a0 += a * bf2f(u.x); a1 += a * bf2f(u.y);
    a2 += a * bf2f(u.z); a3 += a * bf2f(u.w);
  }
  atomicAdd(&out[(size_t)b * H_DIM + h + 0], a0);
  atomicAdd(&out[(size_t)b * H_DIM + h + 1], a1);
  atomicAdd(&out[(size_t)b * H_DIM + h + 2], a2);
  atomicAdd(&out[(size_t)b * H_DIM + h + 3], a3);
}

extern "C" void kernel_launch(void* const* d_in, const int* in_sizes, int n_in,
                              void* d_out, int out_size, void* d_ws, size_t ws_size,
                              hipStream_t stream) {
  (void)in_sizes; (void)n_in; (void)out_size;
  const float* s_t    = (const float*)d_in[0];
  const float* prev_s = (const float*)d_in[1];
  const float* W_prev = (const float*)d_in[2];
  const float* W_s    = (const float*)d_in[3];
  const float* b_s    = (const float*)d_in[4];
  const float* v      = (const float*)d_in[5];
  float* out = (float*)d_out;
  char* ws = (char*)d_ws;
  (void)ws_size;  // requires >= 70647808 bytes

  unsigned short* prevbf = (unsigned short*)(ws + PREVBF_OFF);
  unsigned short* wbf    = (unsigned short*)(ws + WBF_OFF);
  float* dec  = (float*)(ws + DEC_OFF);
  float* part = (float*)(ws + PART_OFF);
  float* at   = (float*)(ws + AT_OFF);

  // zero ct_d region (atomics accumulate into it)
  hipMemsetAsync(d_out, 0, (size_t)B_DIM * H_DIM * sizeof(float), stream);

  prep_kernel<<<2048, 256, 0, stream>>>(prev_s, s_t, W_prev, out, prevbf, wbf);
  dec_kernel<<<256, 256, 0, stream>>>(s_t, W_s, b_s, dec);
  score_gemm<<<2048, 256, 0, stream>>>(prevbf, wbf, dec, v, part);
  softmax_kernel<<<64, 256, 0, stream>>>(part, at);
  ctd_kernel<<<512, 256, 0, stream>>>(prevbf, at, out);
}

// Round 2
// 198.098 us; speedup vs baseline: 1.0253x; 1.0253x over previous
//
#include <hip/hip_runtime.h>
#include <hip/hip_bf16.h>

#define B_DIM 64
#define T_DIM 512
#define H_DIM 1024

typedef __attribute__((ext_vector_type(8))) __bf16 bf16x8;
typedef __attribute__((ext_vector_type(4))) float f32x4;

// ws layout (bytes)
#define PREVBF_OFF 0UL            // 64*512*1024*2 = 67108864
#define WBF_OFF    67108864UL     // 1024*1024*2   =  2097152
#define DEC_OFF    69206016UL     // 64*1024*4     =   262144
#define PART_OFF   69468160UL     // 32768*8*4     =  1048576
#define AT_OFF     70516736UL     // 32768*4       =   131072
// total 70647808 bytes

__device__ __forceinline__ unsigned short f2bf(float x) {
  unsigned u = __float_as_uint(x);
  unsigned r = (u + 0x7FFFu + ((u >> 16) & 1u)) >> 16;  // RNE
  return (unsigned short)r;
}
__device__ __forceinline__ float bf2f(unsigned short u) {
  return __uint_as_float(((unsigned)u) << 16);
}

__device__ __forceinline__ void gload_lds16(const void* g, void* l) {
  __builtin_amdgcn_global_load_lds(
      (const __attribute__((address_space(1))) void*)g,
      (__attribute__((address_space(3))) void*)l, 16, 0, 0);
}

// K1: copy prev_s -> out (concat region), convert prev_s -> bf16 ws,
//     copy s_t -> out tail row, convert W_prev -> bf16 ws.
__global__ void prep_kernel(const float* __restrict__ prev,
                            const float* __restrict__ st,
                            const float* __restrict__ Wp,
                            float* __restrict__ out,
                            unsigned short* __restrict__ prevbf,
                            unsigned short* __restrict__ wbf) {
  const long P4 = (long)B_DIM * T_DIM * H_DIM / 4;  // 8388608
  const long S4 = (long)B_DIM * H_DIM / 4;          // 16384
  const long W4 = (long)H_DIM * H_DIM / 4;          // 262144
  const long total = P4 + S4 + W4;
  long stride = (long)gridDim.x * blockDim.x;
  for (long i = (long)blockIdx.x * blockDim.x + threadIdx.x; i < total; i += stride) {
    if (i < P4) {
      float4 f = ((const float4*)prev)[i];
      long elem = i * 4;
      int b = (int)(elem >> 19);               // /(T*H)
      long rem = elem & ((1L << 19) - 1);
      ((float4*)out)[16384 + (long)b * 131328 + (rem >> 2)] = f;
      ushort4 u;
      u.x = f2bf(f.x); u.y = f2bf(f.y); u.z = f2bf(f.z); u.w = f2bf(f.w);
      ((ushort4*)prevbf)[i] = u;
    } else if (i < P4 + S4) {
      long j = i - P4;
      float4 f = ((const float4*)st)[j];
      long elem = j * 4;
      int b = (int)(elem >> 10);
      int h = (int)(elem & 1023);
      ((float4*)out)[16384 + (long)b * 131328 + 131072 + (h >> 2)] = f;
    } else {
      long j = i - P4 - S4;
      float4 f = ((const float4*)Wp)[j];
      ushort4 u;
      u.x = f2bf(f.x); u.y = f2bf(f.y); u.z = f2bf(f.z); u.w = f2bf(f.w);
      ((ushort4*)wbf)[j] = u;
    }
  }
}

// K2: dec_fea[b][o] = sum_h s_t[b][h]*W_s[o][h] + b_s[o]
__global__ void dec_kernel(const float* __restrict__ st,
                           const float* __restrict__ Ws,
                           const float* __restrict__ bs,
                           float* __restrict__ dec) {
  int tid = threadIdx.x;
  int lane = tid & 63, w = tid >> 6;
  int o = blockIdx.x * 4 + w;
  const float4* wrow = (const float4*)(Ws + (size_t)o * H_DIM);
  float4 w0 = wrow[lane], w1 = wrow[64 + lane], w2 = wrow[128 + lane], w3 = wrow[192 + lane];
  const float4* st4 = (const float4*)st;
  float bias = bs[o];
  #pragma unroll 8
  for (int b = 0; b < B_DIM; b++) {
    const float4* s = st4 + (size_t)b * 256;
    float4 s0 = s[lane], s1 = s[64 + lane], s2 = s[128 + lane], s3 = s[192 + lane];
    float p = w0.x * s0.x + w0.y * s0.y + w0.z * s0.z + w0.w * s0.w
            + w1.x * s1.x + w1.y * s1.y + w1.z * s1.z + w1.w * s1.w
            + w2.x * s2.x + w2.y * s2.y + w2.z * s2.z + w2.w * s2.w
            + w3.x * s3.x + w3.y * s3.y + w3.z * s3.z + w3.w * s3.w;
    p += __shfl_xor(p, 1);  p += __shfl_xor(p, 2);
    p += __shfl_xor(p, 4);  p += __shfl_xor(p, 8);
    p += __shfl_xor(p, 16); p += __shfl_xor(p, 32);
    if (lane == 0) dec[(size_t)b * H_DIM + o] = p + bias;
  }
}

// K3: scores partials. et = A(bf16 prev_s)[M,K] x W(bf16)[N,K]^T, fused
// epilogue: part[m][ntile] = sum_{o in tile} tanh(et+dec)*v[o].
// BK=32, double-buffered LDS, XOR-swizzled (pre-swizzled global source,
// swizzled ds_read — global_load_lds dest stays linear).
__global__ __launch_bounds__(256, 3) void score_gemm(
    const unsigned short* __restrict__ A,   // [32768][1024] bf16
    const unsigned short* __restrict__ Bw,  // [1024][1024] bf16
    const float* __restrict__ dec,          // [64][1024]
    const float* __restrict__ v,            // [1024]
    float* __restrict__ part)               // [32768][8]
{
  __shared__ __align__(16) unsigned short ldsA[2][128 * 32];
  __shared__ __align__(16) unsigned short ldsB[2][128 * 32];

  int orig = blockIdx.x;                       // 2048 blocks
  int swz = (orig & 7) * 256 + (orig >> 3);    // bijective XCD swizzle
  int bm = swz >> 3, bn = swz & 7;

  int tid = threadIdx.x;
  int lane = tid & 63, w = tid >> 6;
  size_t m0 = (size_t)bm * 128;
  int n0 = bn * 128;

  f32x4 acc[2][8];
  #pragma unroll
  for (int i = 0; i < 2; i++)
    #pragma unroll
    for (int j = 0; j < 8; j++) {
      f32x4 z; z.x = 0.f; z.y = 0.f; z.z = 0.f; z.w = 0.f;
      acc[i][j] = z;
    }

  int lr = lane >> 4, lc = lane & 15;

  // staging: 512 16B-chunks per matrix per tile; 2 per thread.
  // chunk idx -> row = idx>>2, sub = idx&3; global sub' = sub ^ ((row>>1)&3)
  int sidx0 = tid, sidx1 = 256 + tid;
  int srow0 = sidx0 >> 2, ssub0 = (sidx0 & 3) ^ ((srow0 >> 1) & 3);
  int srow1 = sidx1 >> 2, ssub1 = (sidx1 & 3) ^ ((srow1 >> 1) & 3);
  const unsigned short* gA0 = A + (m0 + srow0) * 1024 + ssub0 * 8;
  const unsigned short* gA1 = A + (m0 + srow1) * 1024 + ssub1 * 8;
  const unsigned short* gB0 = Bw + (size_t)(n0 + srow0) * 1024 + ssub0 * 8;
  const unsigned short* gB1 = Bw + (size_t)(n0 + srow1) * 1024 + ssub1 * 8;

  // read offsets (ushort units): logical chunk lr at swizzled chunk lr^((r>>1)&3)
  int ra0 = w * 32 + lc;
  int ra1 = ra0 + 16;
  int offA0 = ra0 * 32 + ((lr ^ ((ra0 >> 1) & 3)) << 3);
  int offA1 = ra1 * 32 + ((lr ^ ((ra1 >> 1) & 3)) << 3);
  int offB[8];
  #pragma unroll
  for (int fn = 0; fn < 8; fn++) {
    int rb = fn * 16 + lc;
    offB[fn] = rb * 32 + ((lr ^ ((rb >> 1) & 3)) << 3);
  }

  // prologue: stage tile 0 into buffer 0
  gload_lds16(gA0, &ldsA[0][sidx0 * 8]);
  gload_lds16(gA1, &ldsA[0][sidx1 * 8]);
  gload_lds16(gB0, &ldsB[0][sidx0 * 8]);
  gload_lds16(gB1, &ldsB[0][sidx1 * 8]);
  __syncthreads();  // drains vmcnt+lgkm, then barrier

  #pragma unroll 2
  for (int t = 0; t < 32; t++) {
    int cur = t & 1, nxt = cur ^ 1;
    if (t < 31) {
      int k = (t + 1) * 32;
      gload_lds16(gA0 + k, &ldsA[nxt][sidx0 * 8]);
      gload_lds16(gA1 + k, &ldsA[nxt][sidx1 * 8]);
      gload_lds16(gB0 + k, &ldsB[nxt][sidx0 * 8]);
      gload_lds16(gB1 + k, &ldsB[nxt][sidx1 * 8]);
    }
    bf16x8 a0 = *(const bf16x8*)&ldsA[cur][offA0];
    bf16x8 a1 = *(const bf16x8*)&ldsA[cur][offA1];
    bf16x8 bb[8];
    #pragma unroll
    for (int fn = 0; fn < 8; fn++)
      bb[fn] = *(const bf16x8*)&ldsB[cur][offB[fn]];
    #pragma unroll
    for (int fn = 0; fn < 8; fn++) {
      acc[0][fn] = __builtin_amdgcn_mfma_f32_16x16x32_bf16(a0, bb[fn], acc[0][fn], 0, 0, 0);
      acc[1][fn] = __builtin_amdgcn_mfma_f32_16x16x32_bf16(a1, bb[fn], acc[1][fn], 0, 0, 0);
    }
    __syncthreads();  // staged tile visible; all LDS reads of cur done
  }

  // epilogue: tanh + dot v, reduce over the 128 cols of this n-tile
  int b = (int)(m0 >> 9);  // /T_DIM
  float dv[8], vv[8];
  #pragma unroll
  for (int fn = 0; fn < 8; fn++) {
    int col = n0 + fn * 16 + lc;
    dv[fn] = dec[(size_t)b * H_DIM + col];
    vv[fn] = v[col];
  }
  #pragma unroll
  for (int fm = 0; fm < 2; fm++) {
    #pragma unroll
    for (int r = 0; r < 4; r++) {
      float s = 0.f;
      #pragma unroll
      for (int fn = 0; fn < 8; fn++) {
        float x = acc[fm][fn][r] + dv[fn];
        x = fminf(fmaxf(x, -15.f), 15.f);
        float e = __expf(2.f * x);
        s += vv[fn] * (e - 1.f) * __builtin_amdgcn_rcpf(e + 1.f);
      }
      s += __shfl_xor(s, 1); s += __shfl_xor(s, 2);
      s += __shfl_xor(s, 4); s += __shfl_xor(s, 8);
      if (lc == 0) {
        size_t m = m0 + (size_t)w * 32 + fm * 16 + lr * 4 + r;
        part[m * 8 + bn] = s;
      }
    }
  }
}

// K4: softmax over T per batch row
__global__ void softmax_kernel(const float* __restrict__ part, float* __restrict__ at) {
  int b = blockIdx.x, tid = threadIdx.x;
  __shared__ float sc[512];
  __shared__ float red[8];
  #pragma unroll
  for (int rep = 0; rep < 2; rep++) {
    int t = rep * 256 + tid;
    const float* p = part + ((size_t)b * 512 + t) * 8;
    sc[t] = p[0] + p[1] + p[2] + p[3] + p[4] + p[5] + p[6] + p[7];
  }
  __syncthreads();
  float m = fmaxf(sc[tid], sc[tid + 256]);
  for (int d = 1; d < 64; d <<= 1) m = fmaxf(m, __shfl_xor(m, d));
  if ((tid & 63) == 0) red[tid >> 6] = m;
  __syncthreads();
  m = fmaxf(fmaxf(red[0], red[1]), fmaxf(red[2], red[3]));
  float e0 = __expf(sc[tid] - m), e1 = __expf(sc[tid + 256] - m);
  float s = e0 + e1;
  for (int d = 1; d < 64; d <<= 1) s += __shfl_xor(s, d);
  if ((tid & 63) == 0) red[4 + (tid >> 6)] = s;
  __syncthreads();
  s = red[4] + red[5] + red[6] + red[7];
  float inv = 1.f / s;
  at[(size_t)b * 512 + tid] = e0 * inv;
  at[(size_t)b * 512 + tid + 256] = e1 * inv;
}

// K5: ct_d[b][h] = sum_t at[b][t]*prev_s[b][t][h]  (bf16 prev, fp32 acc)
__global__ void ctd_kernel(const unsigned short* __restrict__ pbf,
                           const float* __restrict__ at, float* __restrict__ out) {
  int blk = blockIdx.x;                 // 512 = 64 b * 8 tchunks
  int b = blk >> 3, tc = blk & 7;
  int tid = threadIdx.x;
  int h = tid * 4;
  float a0 = 0.f, a1 = 0.f, a2 = 0.f, a3 = 0.f;
  const unsigned short* base = pbf + ((size_t)b * T_DIM + (size_t)tc * 64) * H_DIM + h;
  const float* atb = at + (size_t)b * T_DIM + tc * 64;
  #pragma unroll 4
  for (int i = 0; i < 64; i++) {
    float a = atb[i];
    ushort4 u = *(const ushort4*)(base + (size_t)i * H_DIM);
    a0 += a * bf2f(u.x); a1 += a * bf2f(u.y);
    a2 += a * bf2f(u.z); a3 += a * bf2f(u.w);
  }
  atomicAdd(&out[(size_t)b * H_DIM + h + 0], a0);
  atomicAdd(&out[(size_t)b * H_DIM + h + 1], a1);
  atomicAdd(&out[(size_t)b * H_DIM + h + 2], a2);
  atomicAdd(&out[(size_t)b * H_DIM + h + 3], a3);
}

extern "C" void kernel_launch(void* const* d_in, const int* in_sizes, int n_in,
                              void* d_out, int out_size, void* d_ws, size_t ws_size,
                              hipStream_t stream) {
  (void)in_sizes; (void)n_in; (void)out_size;
  const float* s_t    = (const float*)d_in[0];
  const float* prev_s = (const float*)d_in[1];
  const float* W_prev = (const float*)d_in[2];
  const float* W_s    = (const float*)d_in[3];
  const float* b_s    = (const float*)d_in[4];
  const float* v      = (const float*)d_in[5];
  float* out = (float*)d_out;
  char* ws = (char*)d_ws;
  (void)ws_size;  // requires >= 70647808 bytes

  unsigned short* prevbf = (unsigned short*)(ws + PREVBF_OFF);
  unsigned short* wbf    = (unsigned short*)(ws + WBF_OFF);
  float* dec  = (float*)(ws + DEC_OFF);
  float* part = (float*)(ws + PART_OFF);
  float* at   = (float*)(ws + AT_OFF);

  // zero ct_d region (atomics accumulate into it)
  hipMemsetAsync(d_out, 0, (size_t)B_DIM * H_DIM * sizeof(float), stream);

  prep_kernel<<<2048, 256, 0, stream>>>(prev_s, s_t, W_prev, out, prevbf, wbf);
  dec_kernel<<<256, 256, 0, stream>>>(s_t, W_s, b_s, dec);
  score_gemm<<<2048, 256, 0, stream>>>(prevbf, wbf, dec, v, part);
  softmax_kernel<<<64, 256, 0, stream>>>(part, at);
  ctd_kernel<<<512, 256, 0, stream>>>(prevbf, at, out);
}

// Round 3
// 192.994 us; speedup vs baseline: 1.0524x; 1.0264x over previous
//
#include <hip/hip_runtime.h>
#include <hip/hip_bf16.h>

#define B_DIM 64
#define T_DIM 512
#define H_DIM 1024

typedef __attribute__((ext_vector_type(8))) __bf16 bf16x8;
typedef __attribute__((ext_vector_type(4))) float f32x4;

// ws layout (bytes)
#define PREVBF_OFF 0UL            // 64*512*1024*2 = 67108864
#define WBF_OFF    67108864UL     // 1024*1024*2   =  2097152
#define DEC_OFF    69206016UL     // 64*1024*4     =   262144
#define PART_OFF   69468160UL     // 32768*4*4     =   524288
#define AT_OFF     69992448UL     // 32768*4       =   131072
// total 70123520 bytes

__device__ __forceinline__ unsigned short f2bf(float x) {
  unsigned u = __float_as_uint(x);
  unsigned r = (u + 0x7FFFu + ((u >> 16) & 1u)) >> 16;  // RNE
  return (unsigned short)r;
}
__device__ __forceinline__ float bf2f(unsigned short u) {
  return __uint_as_float(((unsigned)u) << 16);
}

__device__ __forceinline__ void gload_lds16(const void* g, void* l) {
  __builtin_amdgcn_global_load_lds(
      (const __attribute__((address_space(1))) void*)g,
      (__attribute__((address_space(3))) void*)l, 16, 0, 0);
}

// K1: copy prev_s -> out (concat region), convert prev_s -> bf16 ws,
//     copy s_t -> out tail row, convert W_prev -> bf16 ws.
__global__ void prep_kernel(const float* __restrict__ prev,
                            const float* __restrict__ st,
                            const float* __restrict__ Wp,
                            float* __restrict__ out,
                            unsigned short* __restrict__ prevbf,
                            unsigned short* __restrict__ wbf) {
  const long P4 = (long)B_DIM * T_DIM * H_DIM / 4;  // 8388608
  const long S4 = (long)B_DIM * H_DIM / 4;          // 16384
  const long W4 = (long)H_DIM * H_DIM / 4;          // 262144
  const long total = P4 + S4 + W4;
  long stride = (long)gridDim.x * blockDim.x;
  for (long i = (long)blockIdx.x * blockDim.x + threadIdx.x; i < total; i += stride) {
    if (i < P4) {
      float4 f = ((const float4*)prev)[i];
      long elem = i * 4;
      int b = (int)(elem >> 19);               // /(T*H)
      long rem = elem & ((1L << 19) - 1);
      ((float4*)out)[16384 + (long)b * 131328 + (rem >> 2)] = f;
      ushort4 u;
      u.x = f2bf(f.x); u.y = f2bf(f.y); u.z = f2bf(f.z); u.w = f2bf(f.w);
      ((ushort4*)prevbf)[i] = u;
    } else if (i < P4 + S4) {
      long j = i - P4;
      float4 f = ((const float4*)st)[j];
      long elem = j * 4;
      int b = (int)(elem >> 10);
      int h = (int)(elem & 1023);
      ((float4*)out)[16384 + (long)b * 131328 + 131072 + (h >> 2)] = f;
    } else {
      long j = i - P4 - S4;
      float4 f = ((const float4*)Wp)[j];
      ushort4 u;
      u.x = f2bf(f.x); u.y = f2bf(f.y); u.z = f2bf(f.z); u.w = f2bf(f.w);
      ((ushort4*)wbf)[j] = u;
    }
  }
}

// K2: dec_fea[b][o] = sum_h s_t[b][h]*W_s[o][h] + b_s[o]
__global__ void dec_kernel(const float* __restrict__ st,
                           const float* __restrict__ Ws,
                           const float* __restrict__ bs,
                           float* __restrict__ dec) {
  int tid = threadIdx.x;
  int lane = tid & 63, w = tid >> 6;
  int o = blockIdx.x * 4 + w;
  const float4* wrow = (const float4*)(Ws + (size_t)o * H_DIM);
  float4 w0 = wrow[lane], w1 = wrow[64 + lane], w2 = wrow[128 + lane], w3 = wrow[192 + lane];
  const float4* st4 = (const float4*)st;
  float bias = bs[o];
  #pragma unroll 8
  for (int b = 0; b < B_DIM; b++) {
    const float4* s = st4 + (size_t)b * 256;
    float4 s0 = s[lane], s1 = s[64 + lane], s2 = s[128 + lane], s3 = s[192 + lane];
    float p = w0.x * s0.x + w0.y * s0.y + w0.z * s0.z + w0.w * s0.w
            + w1.x * s1.x + w1.y * s1.y + w1.z * s1.z + w1.w * s1.w
            + w2.x * s2.x + w2.y * s2.y + w2.z * s2.z + w2.w * s2.w
            + w3.x * s3.x + w3.y * s3.y + w3.z * s3.z + w3.w * s3.w;
    p += __shfl_xor(p, 1);  p += __shfl_xor(p, 2);
    p += __shfl_xor(p, 4);  p += __shfl_xor(p, 8);
    p += __shfl_xor(p, 16); p += __shfl_xor(p, 32);
    if (lane == 0) dec[(size_t)b * H_DIM + o] = p + bias;
  }
}

// K3: 256x256-tile 8-phase GEMM with fused tanh-dot-v epilogue.
// et = A(bf16)[32768,1024] x Bw(bf16)[1024,1024]^T
// part[m][bn] = sum_{cols of 256-tile} tanh(et+dec)*v[col]
__global__ __launch_bounds__(512, 2) void score_gemm(
    const unsigned short* __restrict__ A,
    const unsigned short* __restrict__ Bw,
    const float* __restrict__ dec,
    const float* __restrict__ v,
    float* __restrict__ part)
{
  // [buf][half][128 rows x 64 cols] bf16 ; 64KB + 64KB = 128KB
  __shared__ __align__(16) unsigned short ldsA[2][2][128 * 64];
  __shared__ __align__(16) unsigned short ldsB[2][2][128 * 64];

  int orig = blockIdx.x;                    // 512 blocks
  int swz = (orig & 7) * 64 + (orig >> 3);  // bijective XCD swizzle (512%8==0)
  int bm = swz >> 2, bn = swz & 3;

  int tid = threadIdx.x;
  int lane = tid & 63;
  int w = tid >> 6, wm = w >> 2, wn = w & 3;
  int lr = lane >> 4, lc = lane & 15;
  size_t m0 = (size_t)bm * 256;
  int n0 = bn * 256;

  // staging chunk geometry: 1024 16B chunks per half-tile, 2 per thread
  int c0 = tid, c1 = tid + 512;
  int r0 = c0 >> 3, sb0 = (c0 & 7) ^ (r0 & 7);
  int r1 = c1 >> 3, sb1 = (c1 & 7) ^ (r1 & 7);

  f32x4 acc[8][4];
  #pragma unroll
  for (int i = 0; i < 8; i++)
    #pragma unroll
    for (int j = 0; j < 4; j++) {
      f32x4 z; z.x = 0.f; z.y = 0.f; z.z = 0.f; z.w = 0.f;
      acc[i][j] = z;
    }

  int axor = lc & 7;  // (row & 7) == (lc & 7) since frag row = mf*16 + lc
  int brow0 = (wn & 1) * 64;

  auto stageA = [&](int buf, int h, int T) {
    const unsigned short* g = A + (m0 + h * 128) * 1024 + T * 64;
    gload_lds16(g + (size_t)r0 * 1024 + sb0 * 8, &ldsA[buf][h][c0 * 8]);
    gload_lds16(g + (size_t)r1 * 1024 + sb1 * 8, &ldsA[buf][h][c1 * 8]);
  };
  auto stageB = [&](int buf, int h, int T) {
    const unsigned short* g = Bw + ((size_t)n0 + h * 128) * 1024 + T * 64;
    gload_lds16(g + (size_t)r0 * 1024 + sb0 * 8, &ldsB[buf][h][c0 * 8]);
    gload_lds16(g + (size_t)r1 * 1024 + sb1 * 8, &ldsB[buf][h][c1 * 8]);
  };

  // prologue: tile0 A+B, tile1 B  (12 loads/thread)
  stageA(0, 0, 0); stageA(0, 1, 0);
  stageB(0, 0, 0); stageB(0, 1, 0);
  stageB(1, 0, 1); stageB(1, 1, 1);
  asm volatile("s_waitcnt vmcnt(4)" ::: "memory");  // tile0 halves landed
  __builtin_amdgcn_s_barrier();

  bf16x8 af[4][2];  // current m-group A frags
  bf16x8 bf[4][2];  // all 4 n-frags, live across the tile

  for (int T = 0; T < 16; T++) {
    int buf = T & 1;
    const unsigned short* Ah = &ldsA[buf][wm][0];
    const unsigned short* Bh = &ldsB[buf][wn >> 1][0];

    // ---------- phase 0: read A m0-3 + B n0-1 ; stage A(T+1)h0 ----------
    #pragma unroll
    for (int mf = 0; mf < 4; mf++)
      #pragma unroll
      for (int kk = 0; kk < 2; kk++)
        af[mf][kk] = *(const bf16x8*)&Ah[(mf * 16 + lc) * 64 + (((kk * 4 + lr) ^ axor) << 3)];
    #pragma unroll
    for (int nf = 0; nf < 2; nf++)
      #pragma unroll
      for (int kk = 0; kk < 2; kk++)
        bf[nf][kk] = *(const bf16x8*)&Bh[(brow0 + nf * 16 + lc) * 64 + (((kk * 4 + lr) ^ axor) << 3)];
    if (T + 1 < 16) stageA((T + 1) & 1, 0, T + 1);
    __builtin_amdgcn_s_barrier();
    asm volatile("s_waitcnt lgkmcnt(0)" ::: "memory");
    __builtin_amdgcn_sched_barrier(0);
    __builtin_amdgcn_s_setprio(1);
    #pragma unroll
    for (int mf = 0; mf < 4; mf++)
      #pragma unroll
      for (int nf = 0; nf < 2; nf++)
        #pragma unroll
        for (int kk = 0; kk < 2; kk++)
          acc[mf][nf] = __builtin_amdgcn_mfma_f32_16x16x32_bf16(af[mf][kk], bf[nf][kk], acc[mf][nf], 0, 0, 0);
    __builtin_amdgcn_s_setprio(0);
    __builtin_amdgcn_s_barrier();

    // ---------- phase 1: read B n2-3 ; stage A(T+1)h1 ----------
    #pragma unroll
    for (int nf = 2; nf < 4; nf++)
      #pragma unroll
      for (int kk = 0; kk < 2; kk++)
        bf[nf][kk] = *(const bf16x8*)&Bh[(brow0 + nf * 16 + lc) * 64 + (((kk * 4 + lr) ^ axor) << 3)];
    if (T + 1 < 16) stageA((T + 1) & 1, 1, T + 1);
    __builtin_amdgcn_s_barrier();
    asm volatile("s_waitcnt lgkmcnt(0)" ::: "memory");
    __builtin_amdgcn_sched_barrier(0);
    __builtin_amdgcn_s_setprio(1);
    #pragma unroll
    for (int mf = 0; mf < 4; mf++)
      #pragma unroll
      for (int nf = 2; nf < 4; nf++)
        #pragma unroll
        for (int kk = 0; kk < 2; kk++)
          acc[mf][nf] = __builtin_amdgcn_mfma_f32_16x16x32_bf16(af[mf][kk], bf[nf][kk], acc[mf][nf], 0, 0, 0);
    __builtin_amdgcn_s_setprio(0);
    __builtin_amdgcn_s_barrier();

    // ---------- phase 2: read A m4-7 ; stage B(T+2)h0 ----------
    #pragma unroll
    for (int mf = 0; mf < 4; mf++)
      #pragma unroll
      for (int kk = 0; kk < 2; kk++)
        af[mf][kk] = *(const bf16x8*)&Ah[((mf + 4) * 16 + lc) * 64 + (((kk * 4 + lr) ^ axor) << 3)];
    if (T + 2 < 16) stageB(T & 1, 0, T + 2);
    __builtin_amdgcn_s_barrier();
    asm volatile("s_waitcnt lgkmcnt(0)" ::: "memory");
    __builtin_amdgcn_sched_barrier(0);
    __builtin_amdgcn_s_setprio(1);
    #pragma unroll
    for (int mf = 0; mf < 4; mf++)
      #pragma unroll
      for (int nf = 0; nf < 2; nf++)
        #pragma unroll
        for (int kk = 0; kk < 2; kk++)
          acc[4 + mf][nf] = __builtin_amdgcn_mfma_f32_16x16x32_bf16(af[mf][kk], bf[nf][kk], acc[4 + mf][nf], 0, 0, 0);
    __builtin_amdgcn_s_setprio(0);
    __builtin_amdgcn_s_barrier();

    // ---------- phase 3: no reads ; stage B(T+2)h1 ; tile-boundary vmcnt ----------
    if (T + 2 < 16) stageB(T & 1, 1, T + 2);
    __builtin_amdgcn_s_barrier();
    __builtin_amdgcn_s_setprio(1);
    #pragma unroll
    for (int mf = 0; mf < 4; mf++)
      #pragma unroll
      for (int nf = 2; nf < 4; nf++)
        #pragma unroll
        for (int kk = 0; kk < 2; kk++)
          acc[4 + mf][nf] = __builtin_amdgcn_mfma_f32_16x16x32_bf16(af[mf][kk], bf[nf][kk], acc[4 + mf][nf], 0, 0, 0);
    __builtin_amdgcn_s_setprio(0);
    if (T < 14) {
      asm volatile("s_waitcnt vmcnt(4)" ::: "memory");  // next tile fully landed
    } else {
      asm volatile("s_waitcnt vmcnt(0)" ::: "memory");
    }
    __builtin_amdgcn_s_barrier();
  }

  // epilogue: tanh + dot v over this wave's 64 cols, then 4-way inter-wave
  // reduce (wn) via LDS -> part[m*4 + bn]
  int b = bm >> 1;
  float dv[4], vv[4];
  #pragma unroll
  for (int nf = 0; nf < 4; nf++) {
    int col = n0 + wn * 64 + nf * 16 + lc;
    dv[nf] = dec[(size_t)b * H_DIM + col];
    vv[nf] = v[col];
  }
  float* epi = (float*)&ldsA[0][0][0];  // [256 rows][4 wn] floats = 4KB
  #pragma unroll
  for (int mf = 0; mf < 8; mf++) {
    #pragma unroll
    for (int r = 0; r < 4; r++) {
      float s = 0.f;
      #pragma unroll
      for (int nf = 0; nf < 4; nf++) {
        float x = acc[mf][nf][r] + dv[nf];
        x = fminf(fmaxf(x, -15.f), 15.f);
        float e = __expf(2.f * x);
        s += vv[nf] * (e - 1.f) * __builtin_amdgcn_rcpf(e + 1.f);
      }
      s += __shfl_xor(s, 1); s += __shfl_xor(s, 2);
      s += __shfl_xor(s, 4); s += __shfl_xor(s, 8);
      if (lc == 0) epi[(wm * 128 + mf * 16 + lr * 4 + r) * 4 + wn] = s;
    }
  }
  __syncthreads();
  if (tid < 256) {
    const float* e = &epi[tid * 4];
    part[(m0 + tid) * 4 + bn] = e[0] + e[1] + e[2] + e[3];
  }
}

// K4: softmax over T per batch row (4 partials per row)
__global__ void softmax_kernel(const float* __restrict__ part, float* __restrict__ at) {
  int b = blockIdx.x, tid = threadIdx.x;
  __shared__ float sc[512];
  __shared__ float red[8];
  #pragma unroll
  for (int rep = 0; rep < 2; rep++) {
    int t = rep * 256 + tid;
    const float* p = part + ((size_t)b * 512 + t) * 4;
    sc[t] = p[0] + p[1] + p[2] + p[3];
  }
  __syncthreads();
  float m = fmaxf(sc[tid], sc[tid + 256]);
  for (int d = 1; d < 64; d <<= 1) m = fmaxf(m, __shfl_xor(m, d));
  if ((tid & 63) == 0) red[tid >> 6] = m;
  __syncthreads();
  m = fmaxf(fmaxf(red[0], red[1]), fmaxf(red[2], red[3]));
  float e0 = __expf(sc[tid] - m), e1 = __expf(sc[tid + 256] - m);
  float s = e0 + e1;
  for (int d = 1; d < 64; d <<= 1) s += __shfl_xor(s, d);
  if ((tid & 63) == 0) red[4 + (tid >> 6)] = s;
  __syncthreads();
  s = red[4] + red[5] + red[6] + red[7];
  float inv = 1.f / s;
  at[(size_t)b * 512 + tid] = e0 * inv;
  at[(size_t)b * 512 + tid + 256] = e1 * inv;
}

// K5: ct_d[b][h] = sum_t at[b][t]*prev_s[b][t][h]  (bf16 prev, fp32 acc)
__global__ void ctd_kernel(const unsigned short* __restrict__ pbf,
                           const float* __restrict__ at, float* __restrict__ out) {
  int blk = blockIdx.x;                 // 512 = 64 b * 8 tchunks
  int b = blk >> 3, tc = blk & 7;
  int tid = threadIdx.x;
  int h = tid * 4;
  float a0 = 0.f, a1 = 0.f, a2 = 0.f, a3 = 0.f;
  const unsigned short* base = pbf + ((size_t)b * T_DIM + (size_t)tc * 64) * H_DIM + h;
  const float* atb = at + (size_t)b * T_DIM + tc * 64;
  #pragma unroll 4
  for (int i = 0; i < 64; i++) {
    float a = atb[i];
    ushort4 u = *(const ushort4*)(base + (size_t)i * H_DIM);
    a0 += a * bf2f(u.x); a1 += a * bf2f(u.y);
    a2 += a * bf2f(u.z); a3 += a * bf2f(u.w);
  }
  atomicAdd(&out[(size_t)b * H_DIM + h + 0], a0);
  atomicAdd(&out[(size_t)b * H_DIM + h + 1], a1);
  atomicAdd(&out[(size_t)b * H_DIM + h + 2], a2);
  atomicAdd(&out[(size_t)b * H_DIM + h + 3], a3);
}

extern "C" void kernel_launch(void* const* d_in, const int* in_sizes, int n_in,
                              void* d_out, int out_size, void* d_ws, size_t ws_size,
                              hipStream_t stream) {
  (void)in_sizes; (void)n_in; (void)out_size;
  const float* s_t    = (const float*)d_in[0];
  const float* prev_s = (const float*)d_in[1];
  const float* W_prev = (const float*)d_in[2];
  const float* W_s    = (const float*)d_in[3];
  const float* b_s    = (const float*)d_in[4];
  const float* v      = (const float*)d_in[5];
  float* out = (float*)d_out;
  char* ws = (char*)d_ws;
  (void)ws_size;  // requires >= 70123520 bytes

  unsigned short* prevbf = (unsigned short*)(ws + PREVBF_OFF);
  unsigned short* wbf    = (unsigned short*)(ws + WBF_OFF);
  float* dec  = (float*)(ws + DEC_OFF);
  float* part = (float*)(ws + PART_OFF);
  float* at   = (float*)(ws + AT_OFF);

  // zero ct_d region (atomics accumulate into it)
  hipMemsetAsync(d_out, 0, (size_t)B_DIM * H_DIM * sizeof(float), stream);

  prep_kernel<<<2048, 256, 0, stream>>>(prev_s, s_t, W_prev, out, prevbf, wbf);
  dec_kernel<<<256, 256, 0, stream>>>(s_t, W_s, b_s, dec);
  score_gemm<<<512, 512, 0, stream>>>(prevbf, wbf, dec, v, part);
  softmax_kernel<<<64, 256, 0, stream>>>(part, at);
  ctd_kernel<<<512, 256, 0, stream>>>(prevbf, at, out);
}